// Round 7
// baseline (147.481 us; speedup 1.0000x reference)
//
#include <hip/hip_runtime.h>
#include <stdint.h>

// MessagePassing R7: single-kernel elements-as-columns MFMA pipeline.
// vs R6: (1) PSTR 132->68 dw (bank = 4p+c -> exact 2-way everywhere = free),
// LDS 52.3->26.9 KB -> 6 blocks/CU (24 waves/CU, 2x occupancy); each wave owns
// 16 columns (EL=64/block, no t loop). (2) x loaded only by q==0 lanes (other
// quads' B-rows are A-zero-padded; explicit zeros, never junk -> no NaN).
// (3) prep merged: A-frags baked into LDS plane region at block start
// (2 barriers), then region is recycled; no ws, no serial prep launch.
// Weights^T (+bias row k=36 via constant-1 B row) are A; activations are B
// with col = element; pipeline is wave-private -> no barriers after start.

#define NH 18
#define PSTR 68             // plane stride, dwords; 68%32=4 -> 2-way banks
#define NPL 99              // planes: 5 slots x 18 + 9 tail
// LDS = 99*68*4 = 26928 B -> 6 blocks/CU

typedef _Float16 half8 __attribute__((ext_vector_type(8)));
typedef float float4v __attribute__((ext_vector_type(4)));
union AB { uint32_t u[4]; half8 v; };

__device__ __forceinline__ float fast_tanh(float x) {
    float t = __builtin_amdgcn_exp2f(x * 2.8853900817779268f);
    float r = __builtin_amdgcn_rcpf(t + 1.0f);
    return __builtin_fmaf(-2.0f, r, 1.0f);
}
__device__ __forceinline__ uint32_t pkh(float a, float b) {
    union { _Float16 h[2]; uint32_t u; } z;
    z.h[0] = (_Float16)a; z.h[1] = (_Float16)b; return z.u;
}

#define MFMA16(A, Bv, Cv) __builtin_amdgcn_mfma_f32_16x16x32_f16((A).v, (Bv).v, (Cv), 0, 0, 0)

__global__ __launch_bounds__(256, 6) void mp_mfma(
    const float* __restrict__ x,
    const float* __restrict__ Wf, const float* __restrict__ bf,
    const float* __restrict__ Wm, const float* __restrict__ bm,
    const float* __restrict__ Wu, const float* __restrict__ bu,
    const float* __restrict__ Wr, const float* __restrict__ br,
    float* __restrict__ out, int B)
{
    __shared__ uint32_t lds[NPL * PSTR];
    const int tid = threadIdx.x;
    const int lane = tid & 63, w = tid >> 6;
    const int l15 = lane & 15, q = lane >> 4;

    // ---- in-block frag bake (frags staged in plane region, then recycled) ----
    // frag fi at dw fi*256 + ln*4: A[m=rt*16+(ln&15)][k=ks*32+(ln>>4)*8+j]
    //  fi 0,1: Wf^T rt (k<6 Wf, k==6 bf); fi 2..5: Wm^T rt,ks (k==36 bm);
    //  fi 6..9: WuFold^T rt,ks (k<18 Wu; 18<=k<36 Wu+Wu[+18]; k==36 bu).
    for (int v = tid; v < 640; v += 256) {
        const int fi = v >> 6, ln = v & 63;
        const int fq = ln >> 4, fl = ln & 15;
        int rt, ks, which;
        if (fi < 2)      { which = 0; rt = fi;           ks = 0; }
        else if (fi < 6) { which = 1; rt = (fi - 2) >> 1; ks = (fi - 2) & 1; }
        else             { which = 2; rt = (fi - 6) >> 1; ks = (fi - 6) & 1; }
        const int m = rt * 16 + fl;
        for (int jp = 0; jp < 4; ++jp) {
            float vv[2];
            for (int hh = 0; hh < 2; ++hh) {
                int k = ks * 32 + fq * 8 + jp * 2 + hh;
                float val = 0.0f;
                if (m < NH) {
                    if (which == 0) {
                        if (k < 6) val = Wf[k * NH + m];
                        else if (k == 6) val = bf[m];
                    } else if (which == 1) {
                        if (k < 36) val = Wm[k * NH + m];
                        else if (k == 36) val = bm[m];
                    } else {
                        if (k < NH) val = Wu[k * NH + m];
                        else if (k < 36) val = Wu[k * NH + m] + Wu[(k + NH) * NH + m];
                        else if (k == 36) val = bu[m];
                    }
                }
                vv[hh] = val;
            }
            lds[fi * 256 + ln * 4 + jp] = pkh(vv[0], vv[1]);
        }
    }
    __syncthreads();
    AB F[10];
    #pragma unroll
    for (int f = 0; f < 10; ++f) {
        const int o = f * 256 + lane * 4;
        F[f].u[0] = lds[o];     F[f].u[1] = lds[o + 1];
        F[f].u[2] = lds[o + 2]; F[f].u[3] = lds[o + 3];
    }
    __syncthreads();   // frag region is dead; planes reused by pipeline below

    // readout tables: direct global (90 floats, L1-hot after first wave)
    float wrA[5][4], wrB[5][2];
    #pragma unroll
    for (int n = 0; n < 5; ++n) {
        #pragma unroll
        for (int r = 0; r < 4; ++r) wrA[n][r] = Wr[n * NH + q * 4 + r];
        #pragma unroll
        for (int r = 0; r < 2; ++r) wrB[n][r] = (q == 0) ? Wr[n * NH + 16 + r] : 0.0f;
    }
    const float brv = br[0];
    const uint32_t ONE = 0x00003C00u;          // f16 pair (1.0, 0.0): bias row
    const float4v Z = {0.f, 0.f, 0.f, 0.f};

    const int c = w * 16 + l15;                // column = element (wave-private)
    const long long eg = (long long)blockIdx.x * 64 + c;

    // x only on q==0 (B-rows k>=8 are A-zero-padded; feed explicit zeros)
    uint32_t xpk[5][4];
    #pragma unroll
    for (int n = 0; n < 5; ++n) {
        xpk[n][0] = 0; xpk[n][1] = 0; xpk[n][2] = 0;
        xpk[n][3] = (q == 0) ? ONE : 0;
    }
    if (q == 0 && eg < (long long)B) {
        const float2* xp = (const float2*)x + eg * 15;
        #pragma unroll
        for (int n = 0; n < 5; ++n) {
            float2 a = xp[n * 3], b2 = xp[n * 3 + 1], d = xp[n * 3 + 2];
            xpk[n][0] = pkh(a.x, a.y); xpk[n][1] = pkh(b2.x, b2.y);
            xpk[n][2] = pkh(d.x, d.y);
        }
    }
    const int qc = q * 4 * PSTR + c;   // B-read term (plane += q*4)
    const int qw = q * 2 * PSTR + c;   // C-write term (plane += q*2)

    // ---- stage 1: h_n = tanh([x_n|1] @ [Wf;bf]) ----
    // h_n -> slot n first half (plane n*18) AND slot n-1 second half
    // ((n-1)*18+9; n=0 -> 81) AND (n==0) tail 90.
    #pragma unroll
    for (int n = 0; n < 5; ++n) {
        AB bx; bx.u[0] = xpk[n][0]; bx.u[1] = xpk[n][1];
               bx.u[2] = xpk[n][2]; bx.u[3] = xpk[n][3];
        float4v C0 = MFMA16(F[0], bx, Z);
        float4v C1 = MFMA16(F[1], bx, Z);
        uint32_t p0 = pkh(fast_tanh(C0[0]), fast_tanh(C0[1]));
        uint32_t p1 = pkh(fast_tanh(C0[2]), fast_tanh(C0[3]));
        uint32_t p2 = pkh(fast_tanh(C1[0]), fast_tanh(C1[1]));
        const int P1 = n * 18;
        const int P2 = (n == 0) ? 81 : (n - 1) * 18 + 9;
        lds[P1 * PSTR + qw] = p0; lds[(P1 + 1) * PSTR + qw] = p1;
        lds[P2 * PSTR + qw] = p0; lds[(P2 + 1) * PSTR + qw] = p1;
        if (q == 0) { lds[(P1 + 8) * PSTR + c] = p2; lds[(P2 + 8) * PSTR + c] = p2; }
        if (n == 0) {
            lds[90 * PSTR + qw] = p0; lds[91 * PSTR + qw] = p1;
            if (q == 0) lds[98 * PSTR + c] = p2;
        }
    }

    // ---- stage 2: M_n = tanh([h_n|h_{n+1}|1] @ [Wm;bm]) ----
    // reads slot n (branch-free); M_n overwrites dead h_{n+1} copy at
    // planes n*18+9..17 (read-before-write, program-ordered per wave).
    #pragma unroll
    for (int n = 0; n < 5; ++n) {
        const int vb = n * 18;
        AB b0, b1;
        b0.u[0] = lds[vb * PSTR + qc];       b0.u[1] = lds[(vb + 1) * PSTR + qc];
        b0.u[2] = lds[(vb + 2) * PSTR + qc]; b0.u[3] = lds[(vb + 3) * PSTR + qc];
        b1.u[0] = lds[(vb + 16) * PSTR + c]; b1.u[1] = lds[(vb + 17) * PSTR + c];
        b1.u[2] = ONE; b1.u[3] = 0;
        float4v C0 = MFMA16(F[2], b0, Z); C0 = MFMA16(F[3], b1, C0);
        float4v C1 = MFMA16(F[4], b0, Z); C1 = MFMA16(F[5], b1, C1);
        uint32_t p0 = pkh(fast_tanh(C0[0]), fast_tanh(C0[1]));
        uint32_t p1 = pkh(fast_tanh(C0[2]), fast_tanh(C0[3]));
        uint32_t p2 = pkh(fast_tanh(C1[0]), fast_tanh(C1[1]));
        const int PM = n * 18 + 9;
        lds[PM * PSTR + qw] = p0; lds[(PM + 1) * PSTR + qw] = p1;
        if (q == 0) lds[(PM + 8) * PSTR + c] = p2;
    }

    // ---- stage 3: U2_n = tanh([M_{n-1}|h_n|1] @ [WuFold;bu]); readout ----
    // [M_{n-1}|h_n] contiguous at planes (n-1)*18+9 (n=0 -> 81..98).
    float rc = 0.0f;
    #pragma unroll
    for (int n = 0; n < 5; ++n) {
        const int vb = (n == 0) ? 81 : (n - 1) * 18 + 9;
        AB b0, b1;
        b0.u[0] = lds[vb * PSTR + qc];       b0.u[1] = lds[(vb + 1) * PSTR + qc];
        b0.u[2] = lds[(vb + 2) * PSTR + qc]; b0.u[3] = lds[(vb + 3) * PSTR + qc];
        b1.u[0] = lds[(vb + 16) * PSTR + c]; b1.u[1] = lds[(vb + 17) * PSTR + c];
        b1.u[2] = ONE; b1.u[3] = 0;
        float4v C0 = MFMA16(F[6], b0, Z); C0 = MFMA16(F[7], b1, C0);
        float4v C1 = MFMA16(F[8], b0, Z); C1 = MFMA16(F[9], b1, C1);
        rc = __builtin_fmaf(fast_tanh(C0[0]), wrA[n][0], rc);
        rc = __builtin_fmaf(fast_tanh(C0[1]), wrA[n][1], rc);
        rc = __builtin_fmaf(fast_tanh(C0[2]), wrA[n][2], rc);
        rc = __builtin_fmaf(fast_tanh(C0[3]), wrA[n][3], rc);
        rc = __builtin_fmaf(fast_tanh(C1[0]), wrB[n][0], rc);
        rc = __builtin_fmaf(fast_tanh(C1[1]), wrB[n][1], rc);
    }

    // ---- readout: sum the 4 quads of each column ----
    float s = rc;
    s += __shfl_xor(s, 16, 64);
    s += __shfl_xor(s, 32, 64);
    if (q == 0 && eg < (long long)B) out[eg] = s + brv;
}

extern "C" void kernel_launch(void* const* d_in, const int* in_sizes, int n_in,
                              void* d_out, int out_size, void* d_ws, size_t ws_size,
                              hipStream_t stream) {
    const float* x  = (const float*)d_in[0];
    const float* Wf = (const float*)d_in[1];
    const float* bf = (const float*)d_in[2];
    const float* Wm = (const float*)d_in[3];
    const float* bm = (const float*)d_in[4];
    const float* Wu = (const float*)d_in[5];
    const float* bu = (const float*)d_in[6];
    const float* Wr = (const float*)d_in[7];
    const float* br = (const float*)d_in[8];
    float* out = (float*)d_out;
    const int B = in_sizes[0] / 30;
    const int grid = (B + 63) / 64;
    mp_mfma<<<grid, 256, 0, stream>>>(x, Wf, bf, Wm, bm, Wu, bu, Wr, br, out, B);
}

// Round 8
// 128.063 us; speedup vs baseline: 1.1516x; 1.1516x over previous
//
#include <hip/hip_runtime.h>
#include <stdint.h>

// MessagePassing R8: R7 structure with the register/occupancy trade fixed.
// R7's __launch_bounds__(256,6) capped VGPR ~85 under ~115 demand -> compiler
// spilled to scratch: WRITE_SIZE 91 MB (out is 1 MB!), FETCH 42 MB, 73 us.
// R8: (256,4) -> 128 VGPR cap, zero spill, 4 blocks/CU (16 waves/CU; R6 had
// 12). wr-table/br loads moved after stage 2 to shorten live ranges.
// Elements-as-columns MFMA pipeline, zero barriers after the frag bake.

#define NH 18
#define PSTR 68             // plane stride, dwords; 68%32=4 -> 2-way banks (free)
#define NPL 99              // planes: 5 slots x 18 + 9 tail
// LDS = 99*68*4 = 26928 B

typedef _Float16 half8 __attribute__((ext_vector_type(8)));
typedef float float4v __attribute__((ext_vector_type(4)));
union AB { uint32_t u[4]; half8 v; };

__device__ __forceinline__ float fast_tanh(float x) {
    float t = __builtin_amdgcn_exp2f(x * 2.8853900817779268f);
    float r = __builtin_amdgcn_rcpf(t + 1.0f);
    return __builtin_fmaf(-2.0f, r, 1.0f);
}
__device__ __forceinline__ uint32_t pkh(float a, float b) {
    union { _Float16 h[2]; uint32_t u; } z;
    z.h[0] = (_Float16)a; z.h[1] = (_Float16)b; return z.u;
}

#define MFMA16(A, Bv, Cv) __builtin_amdgcn_mfma_f32_16x16x32_f16((A).v, (Bv).v, (Cv), 0, 0, 0)

__global__ __launch_bounds__(256, 4) void mp_mfma(
    const float* __restrict__ x,
    const float* __restrict__ Wf, const float* __restrict__ bf,
    const float* __restrict__ Wm, const float* __restrict__ bm,
    const float* __restrict__ Wu, const float* __restrict__ bu,
    const float* __restrict__ Wr, const float* __restrict__ br,
    float* __restrict__ out, int B)
{
    __shared__ uint32_t lds[NPL * PSTR];
    const int tid = threadIdx.x;
    const int lane = tid & 63, w = tid >> 6;
    const int l15 = lane & 15, q = lane >> 4;

    // ---- in-block frag bake (staged in plane region, then recycled) ----
    // frag fi at dw fi*256 + ln*4: A[m=rt*16+(ln&15)][k=ks*32+(ln>>4)*8+j]
    //  fi 0,1: Wf^T rt (k<6 Wf, k==6 bf); fi 2..5: Wm^T rt,ks (k==36 bm);
    //  fi 6..9: WuFold^T rt,ks (k<18 Wu; 18<=k<36 Wu+Wu[+18]; k==36 bu).
    for (int v = tid; v < 640; v += 256) {
        const int fi = v >> 6, ln = v & 63;
        const int fq = ln >> 4, fl = ln & 15;
        int rt, ks, which;
        if (fi < 2)      { which = 0; rt = fi;            ks = 0; }
        else if (fi < 6) { which = 1; rt = (fi - 2) >> 1; ks = (fi - 2) & 1; }
        else             { which = 2; rt = (fi - 6) >> 1; ks = (fi - 6) & 1; }
        const int m = rt * 16 + fl;
        for (int jp = 0; jp < 4; ++jp) {
            float vv[2];
            for (int hh = 0; hh < 2; ++hh) {
                int k = ks * 32 + fq * 8 + jp * 2 + hh;
                float val = 0.0f;
                if (m < NH) {
                    if (which == 0) {
                        if (k < 6) val = Wf[k * NH + m];
                        else if (k == 6) val = bf[m];
                    } else if (which == 1) {
                        if (k < 36) val = Wm[k * NH + m];
                        else if (k == 36) val = bm[m];
                    } else {
                        if (k < NH) val = Wu[k * NH + m];
                        else if (k < 36) val = Wu[k * NH + m] + Wu[(k + NH) * NH + m];
                        else if (k == 36) val = bu[m];
                    }
                }
                vv[hh] = val;
            }
            lds[fi * 256 + ln * 4 + jp] = pkh(vv[0], vv[1]);
        }
    }
    __syncthreads();
    AB F[10];
    #pragma unroll
    for (int f = 0; f < 10; ++f) {
        const int o = f * 256 + lane * 4;
        F[f].u[0] = lds[o];     F[f].u[1] = lds[o + 1];
        F[f].u[2] = lds[o + 2]; F[f].u[3] = lds[o + 3];
    }
    __syncthreads();   // frag region dead; planes reused by pipeline below

    const uint32_t ONE = 0x00003C00u;          // f16 pair (1.0, 0.0): bias row
    const float4v Z = {0.f, 0.f, 0.f, 0.f};

    const int c = w * 16 + l15;                // column = element (wave-private)
    const long long eg = (long long)blockIdx.x * 64 + c;

    // x only on q==0 (B-rows k>=8 are A-zero-padded; explicit zeros, no junk)
    uint32_t xpk[5][4];
    #pragma unroll
    for (int n = 0; n < 5; ++n) {
        xpk[n][0] = 0; xpk[n][1] = 0; xpk[n][2] = 0;
        xpk[n][3] = (q == 0) ? ONE : 0;
    }
    if (q == 0 && eg < (long long)B) {
        const float2* xp = (const float2*)x + eg * 15;
        #pragma unroll
        for (int n = 0; n < 5; ++n) {
            float2 a = xp[n * 3], b2 = xp[n * 3 + 1], d = xp[n * 3 + 2];
            xpk[n][0] = pkh(a.x, a.y); xpk[n][1] = pkh(b2.x, b2.y);
            xpk[n][2] = pkh(d.x, d.y);
        }
    }
    const int qc = q * 4 * PSTR + c;   // B-read term (plane += q*4)
    const int qw = q * 2 * PSTR + c;   // C-write term (plane += q*2)

    // ---- stage 1: h_n = tanh([x_n|1] @ [Wf;bf]) ----
    // h_n -> slot n first half (plane n*18) AND slot n-1 second half
    // ((n-1)*18+9; n=0 -> 81) AND (n==0) tail 90.
    #pragma unroll
    for (int n = 0; n < 5; ++n) {
        AB bx; bx.u[0] = xpk[n][0]; bx.u[1] = xpk[n][1];
               bx.u[2] = xpk[n][2]; bx.u[3] = xpk[n][3];
        float4v C0 = MFMA16(F[0], bx, Z);
        float4v C1 = MFMA16(F[1], bx, Z);
        uint32_t p0 = pkh(fast_tanh(C0[0]), fast_tanh(C0[1]));
        uint32_t p1 = pkh(fast_tanh(C0[2]), fast_tanh(C0[3]));
        uint32_t p2 = pkh(fast_tanh(C1[0]), fast_tanh(C1[1]));
        const int P1 = n * 18;
        const int P2 = (n == 0) ? 81 : (n - 1) * 18 + 9;
        lds[P1 * PSTR + qw] = p0; lds[(P1 + 1) * PSTR + qw] = p1;
        lds[P2 * PSTR + qw] = p0; lds[(P2 + 1) * PSTR + qw] = p1;
        if (q == 0) { lds[(P1 + 8) * PSTR + c] = p2; lds[(P2 + 8) * PSTR + c] = p2; }
        if (n == 0) {
            lds[90 * PSTR + qw] = p0; lds[91 * PSTR + qw] = p1;
            if (q == 0) lds[98 * PSTR + c] = p2;
        }
    }

    // ---- stage 2: M_n = tanh([h_n|h_{n+1}|1] @ [Wm;bm]) ----
    // reads slot n (branch-free); M_n overwrites dead h_{n+1} copy at
    // planes n*18+9..17 (read-before-write, program-ordered per wave).
    #pragma unroll
    for (int n = 0; n < 5; ++n) {
        const int vb = n * 18;
        AB b0, b1;
        b0.u[0] = lds[vb * PSTR + qc];       b0.u[1] = lds[(vb + 1) * PSTR + qc];
        b0.u[2] = lds[(vb + 2) * PSTR + qc]; b0.u[3] = lds[(vb + 3) * PSTR + qc];
        b1.u[0] = lds[(vb + 16) * PSTR + c]; b1.u[1] = lds[(vb + 17) * PSTR + c];
        b1.u[2] = ONE; b1.u[3] = 0;
        float4v C0 = MFMA16(F[2], b0, Z); C0 = MFMA16(F[3], b1, C0);
        float4v C1 = MFMA16(F[4], b0, Z); C1 = MFMA16(F[5], b1, C1);
        uint32_t p0 = pkh(fast_tanh(C0[0]), fast_tanh(C0[1]));
        uint32_t p1 = pkh(fast_tanh(C0[2]), fast_tanh(C0[3]));
        uint32_t p2 = pkh(fast_tanh(C1[0]), fast_tanh(C1[1]));
        const int PM = n * 18 + 9;
        lds[PM * PSTR + qw] = p0; lds[(PM + 1) * PSTR + qw] = p1;
        if (q == 0) lds[(PM + 8) * PSTR + c] = p2;
    }

    // readout tables: loaded HERE (only live through stage 3 -> less pressure
    // during stages 1-2; 90 floats, L1-hot after first wave)
    float wrA[5][4], wrB[5][2];
    #pragma unroll
    for (int n = 0; n < 5; ++n) {
        #pragma unroll
        for (int r = 0; r < 4; ++r) wrA[n][r] = Wr[n * NH + q * 4 + r];
        #pragma unroll
        for (int r = 0; r < 2; ++r) wrB[n][r] = (q == 0) ? Wr[n * NH + 16 + r] : 0.0f;
    }

    // ---- stage 3: U2_n = tanh([M_{n-1}|h_n|1] @ [WuFold;bu]); readout ----
    // [M_{n-1}|h_n] contiguous at planes (n-1)*18+9 (n=0 -> 81..98).
    float rc = 0.0f;
    #pragma unroll
    for (int n = 0; n < 5; ++n) {
        const int vb = (n == 0) ? 81 : (n - 1) * 18 + 9;
        AB b0, b1;
        b0.u[0] = lds[vb * PSTR + qc];       b0.u[1] = lds[(vb + 1) * PSTR + qc];
        b0.u[2] = lds[(vb + 2) * PSTR + qc]; b0.u[3] = lds[(vb + 3) * PSTR + qc];
        b1.u[0] = lds[(vb + 16) * PSTR + c]; b1.u[1] = lds[(vb + 17) * PSTR + c];
        b1.u[2] = ONE; b1.u[3] = 0;
        float4v C0 = MFMA16(F[6], b0, Z); C0 = MFMA16(F[7], b1, C0);
        float4v C1 = MFMA16(F[8], b0, Z); C1 = MFMA16(F[9], b1, C1);
        rc = __builtin_fmaf(fast_tanh(C0[0]), wrA[n][0], rc);
        rc = __builtin_fmaf(fast_tanh(C0[1]), wrA[n][1], rc);
        rc = __builtin_fmaf(fast_tanh(C0[2]), wrA[n][2], rc);
        rc = __builtin_fmaf(fast_tanh(C0[3]), wrA[n][3], rc);
        rc = __builtin_fmaf(fast_tanh(C1[0]), wrB[n][0], rc);
        rc = __builtin_fmaf(fast_tanh(C1[1]), wrB[n][1], rc);
    }

    // ---- readout: sum the 4 quads of each column ----
    float s = rc;
    s += __shfl_xor(s, 16, 64);
    s += __shfl_xor(s, 32, 64);
    if (q == 0 && eg < (long long)B) out[eg] = s + br[0];
}

extern "C" void kernel_launch(void* const* d_in, const int* in_sizes, int n_in,
                              void* d_out, int out_size, void* d_ws, size_t ws_size,
                              hipStream_t stream) {
    const float* x  = (const float*)d_in[0];
    const float* Wf = (const float*)d_in[1];
    const float* bf = (const float*)d_in[2];
    const float* Wm = (const float*)d_in[3];
    const float* bm = (const float*)d_in[4];
    const float* Wu = (const float*)d_in[5];
    const float* bu = (const float*)d_in[6];
    const float* Wr = (const float*)d_in[7];
    const float* br = (const float*)d_in[8];
    float* out = (float*)d_out;
    const int B = in_sizes[0] / 30;
    const int grid = (B + 63) / 64;
    mp_mfma<<<grid, 256, 0, stream>>>(x, Wf, bf, Wm, bm, Wu, bu, Wr, br, out, B);
}

// Round 10
// 111.066 us; speedup vs baseline: 1.3279x; 1.1530x over previous
//
#include <hip/hip_runtime.h>
#include <stdint.h>

// MessagePassing R10: R9 with the cvt_pkrtz builtin type fixed (__fp16 vector,
// not _Float16). Structure: prep kernel bakes pre-scaled (2*log2e) transposed
// A-frags + bias row into ws; main kernel is the elements-as-columns f16 MFMA
// pipeline with wave-private columns, ZERO barriers, LDS 26.9 KB,
// __launch_bounds__(256,4) (VGPR cap 128 -> no spill).

#define NH 18
#define PSTR 68             // plane stride, dwords; 68%32=4 -> 2-way banks (free)
#define NPL 99              // planes: 5 slots x 18 + 9 tail
#define TSCALE 2.8853900817779268f   // 2*log2(e), baked into A-frags
// LDS = 99*68*4 = 26928 B

typedef _Float16 half8 __attribute__((ext_vector_type(8)));
typedef __fp16 fp16x2 __attribute__((ext_vector_type(2)));
typedef float float4v __attribute__((ext_vector_type(4)));
union AB { uint32_t u[4]; half8 v; };

__device__ __forceinline__ float tanh_pre(float z) {
    // z is pre-scaled by 2*log2(e): tanh = 1 - 2/(2^z + 1)
    float t = __builtin_amdgcn_exp2f(z);
    float r = __builtin_amdgcn_rcpf(t + 1.0f);
    return __builtin_fmaf(-2.0f, r, 1.0f);
}
__device__ __forceinline__ uint32_t pk2(float a, float b) {
    union { fp16x2 h; uint32_t u; } z;
    z.h = __builtin_amdgcn_cvt_pkrtz(a, b);   // single v_cvt_pkrtz_f16_f32
    return z.u;
}

// ---- prep: bake pre-scaled transposed A-frags (bias row k=36) into ws ----
// frag fi at dw fi*256 + ln*4: A[m=rt*16+(ln&15)][k=ks*32+(ln>>4)*8+j]
//  fi 0,1: Wf^T rt (k<6 Wf, k==6 bf); fi 2..5: Wm^T rt,ks (k==36 bm);
//  fi 6..9: WuFold^T rt,ks (k<18 Wu; 18<=k<36 Wu+Wu[+18]; k==36 bu).
// All values scaled by TSCALE (tanh input pre-scale rides the MFMA).
__global__ __launch_bounds__(640) void prep_kernel(
    const float* __restrict__ Wf, const float* __restrict__ bf,
    const float* __restrict__ Wm, const float* __restrict__ bm,
    const float* __restrict__ Wu, const float* __restrict__ bu,
    uint32_t* __restrict__ ws)
{
    const int tid = threadIdx.x;
    const int fi = tid >> 6, ln = tid & 63;
    const int fq = ln >> 4, fl = ln & 15;
    int rt, ks, which;
    if (fi < 2)      { which = 0; rt = fi;            ks = 0; }
    else if (fi < 6) { which = 1; rt = (fi - 2) >> 1; ks = (fi - 2) & 1; }
    else             { which = 2; rt = (fi - 6) >> 1; ks = (fi - 6) & 1; }
    const int m = rt * 16 + fl;
    for (int jp = 0; jp < 4; ++jp) {
        float vv[2];
        for (int hh = 0; hh < 2; ++hh) {
            int k = ks * 32 + fq * 8 + jp * 2 + hh;
            float val = 0.0f;
            if (m < NH) {
                if (which == 0) {
                    if (k < 6) val = Wf[k * NH + m];
                    else if (k == 6) val = bf[m];
                } else if (which == 1) {
                    if (k < 36) val = Wm[k * NH + m];
                    else if (k == 36) val = bm[m];
                } else {
                    if (k < NH) val = Wu[k * NH + m];
                    else if (k < 36) val = Wu[k * NH + m] + Wu[(k + NH) * NH + m];
                    else if (k == 36) val = bu[m];
                }
            }
            vv[hh] = val * TSCALE;
        }
        ws[fi * 256 + ln * 4 + jp] = pk2(vv[0], vv[1]);
    }
}

#define MFMA16(A, Bv, Cv) __builtin_amdgcn_mfma_f32_16x16x32_f16((A).v, (Bv).v, (Cv), 0, 0, 0)

__global__ __launch_bounds__(256, 4) void mp_mfma(
    const float* __restrict__ x,
    const float* __restrict__ Wr, const float* __restrict__ br,
    const uint32_t* __restrict__ ws, float* __restrict__ out, int B)
{
    __shared__ uint32_t lds[NPL * PSTR];
    const int tid = threadIdx.x;
    const int lane = tid & 63, w = tid >> 6;
    const int l15 = lane & 15, q = lane >> 4;

    // frags: 10 coalesced dwordx4 from ws (L2-resident)
    AB F[10];
    #pragma unroll
    for (int f = 0; f < 10; ++f) {
        const uint32_t* p = ws + f * 256 + lane * 4;
        F[f].u[0] = p[0]; F[f].u[1] = p[1]; F[f].u[2] = p[2]; F[f].u[3] = p[3];
    }

    const uint32_t ONE = 0x00003C00u;          // f16 pair (1.0, 0.0): bias row
    const float4v Z = {0.f, 0.f, 0.f, 0.f};

    const int c = w * 16 + l15;                // column = element (wave-private)
    const long long eg = (long long)blockIdx.x * 64 + c;

    // x only on q==0 (B-rows k>=8 are A-zero-padded; explicit zeros, no junk)
    uint32_t xpk[5][4];
    #pragma unroll
    for (int n = 0; n < 5; ++n) {
        xpk[n][0] = 0; xpk[n][1] = 0; xpk[n][2] = 0;
        xpk[n][3] = (q == 0) ? ONE : 0;
    }
    if (q == 0 && eg < (long long)B) {
        const float2* xp = (const float2*)x + eg * 15;
        #pragma unroll
        for (int n = 0; n < 5; ++n) {
            float2 a = xp[n * 3], b2 = xp[n * 3 + 1], d = xp[n * 3 + 2];
            xpk[n][0] = pk2(a.x, a.y); xpk[n][1] = pk2(b2.x, b2.y);
            xpk[n][2] = pk2(d.x, d.y);
        }
    }
    const int qc = q * 4 * PSTR + c;   // B-read term (plane += q*4)
    const int qw = q * 2 * PSTR + c;   // C-write term (plane += q*2)

    // ---- stage 1: h_n = tanh([x_n|1] @ [Wf;bf]') ----
    // h_n -> slot n first half (plane n*18) AND slot n-1 second half
    // ((n-1)*18+9; n=0 -> 81) AND (n==0) tail 90.
    #pragma unroll
    for (int n = 0; n < 5; ++n) {
        AB bx; bx.u[0] = xpk[n][0]; bx.u[1] = xpk[n][1];
               bx.u[2] = xpk[n][2]; bx.u[3] = xpk[n][3];
        float4v C0 = MFMA16(F[0], bx, Z);
        float4v C1 = MFMA16(F[1], bx, Z);
        uint32_t p0 = pk2(tanh_pre(C0[0]), tanh_pre(C0[1]));
        uint32_t p1 = pk2(tanh_pre(C0[2]), tanh_pre(C0[3]));
        uint32_t p2 = pk2(tanh_pre(C1[0]), tanh_pre(C1[1]));
        const int P1 = n * 18;
        const int P2 = (n == 0) ? 81 : (n - 1) * 18 + 9;
        lds[P1 * PSTR + qw] = p0; lds[(P1 + 1) * PSTR + qw] = p1;
        lds[P2 * PSTR + qw] = p0; lds[(P2 + 1) * PSTR + qw] = p1;
        if (q == 0) { lds[(P1 + 8) * PSTR + c] = p2; lds[(P2 + 8) * PSTR + c] = p2; }
        if (n == 0) {
            lds[90 * PSTR + qw] = p0; lds[91 * PSTR + qw] = p1;
            if (q == 0) lds[98 * PSTR + c] = p2;
        }
    }

    // ---- stage 2: M_n = tanh([h_n|h_{n+1}|1] @ [Wm;bm]') ----
    // reads slot n (branch-free); M_n overwrites dead h_{n+1} copy at
    // planes n*18+9..17 (read-before-write, program-ordered per wave).
    #pragma unroll
    for (int n = 0; n < 5; ++n) {
        const int vb = n * 18;
        AB b0, b1;
        b0.u[0] = lds[vb * PSTR + qc];       b0.u[1] = lds[(vb + 1) * PSTR + qc];
        b0.u[2] = lds[(vb + 2) * PSTR + qc]; b0.u[3] = lds[(vb + 3) * PSTR + qc];
        b1.u[0] = lds[(vb + 16) * PSTR + c]; b1.u[1] = lds[(vb + 17) * PSTR + c];
        b1.u[2] = ONE; b1.u[3] = 0;
        float4v C0 = MFMA16(F[2], b0, Z); C0 = MFMA16(F[3], b1, C0);
        float4v C1 = MFMA16(F[4], b0, Z); C1 = MFMA16(F[5], b1, C1);
        uint32_t p0 = pk2(tanh_pre(C0[0]), tanh_pre(C0[1]));
        uint32_t p1 = pk2(tanh_pre(C0[2]), tanh_pre(C0[3]));
        uint32_t p2 = pk2(tanh_pre(C1[0]), tanh_pre(C1[1]));
        const int PM = n * 18 + 9;
        lds[PM * PSTR + qw] = p0; lds[(PM + 1) * PSTR + qw] = p1;
        if (q == 0) lds[(PM + 8) * PSTR + c] = p2;
    }

    // readout tables: loaded here (live only through stage 3; L1-hot)
    float wrA[5][4], wrB[5][2];
    #pragma unroll
    for (int n = 0; n < 5; ++n) {
        #pragma unroll
        for (int r = 0; r < 4; ++r) wrA[n][r] = Wr[n * NH + q * 4 + r];
        #pragma unroll
        for (int r = 0; r < 2; ++r) wrB[n][r] = (q == 0) ? Wr[n * NH + 16 + r] : 0.0f;
    }

    // ---- stage 3: U2_n = tanh([M_{n-1}|h_n|1] @ [WuFold;bu]'); readout ----
    // [M_{n-1}|h_n] contiguous at planes (n-1)*18+9 (n=0 -> 81..98).
    float rc = 0.0f;
    #pragma unroll
    for (int n = 0; n < 5; ++n) {
        const int vb = (n == 0) ? 81 : (n - 1) * 18 + 9;
        AB b0, b1;
        b0.u[0] = lds[vb * PSTR + qc];       b0.u[1] = lds[(vb + 1) * PSTR + qc];
        b0.u[2] = lds[(vb + 2) * PSTR + qc]; b0.u[3] = lds[(vb + 3) * PSTR + qc];
        b1.u[0] = lds[(vb + 16) * PSTR + c]; b1.u[1] = lds[(vb + 17) * PSTR + c];
        b1.u[2] = ONE; b1.u[3] = 0;
        float4v C0 = MFMA16(F[6], b0, Z); C0 = MFMA16(F[7], b1, C0);
        float4v C1 = MFMA16(F[8], b0, Z); C1 = MFMA16(F[9], b1, C1);
        rc = __builtin_fmaf(tanh_pre(C0[0]), wrA[n][0], rc);
        rc = __builtin_fmaf(tanh_pre(C0[1]), wrA[n][1], rc);
        rc = __builtin_fmaf(tanh_pre(C0[2]), wrA[n][2], rc);
        rc = __builtin_fmaf(tanh_pre(C0[3]), wrA[n][3], rc);
        rc = __builtin_fmaf(tanh_pre(C1[0]), wrB[n][0], rc);
        rc = __builtin_fmaf(tanh_pre(C1[1]), wrB[n][1], rc);
    }

    // ---- readout: sum the 4 quads of each column ----
    float s = rc;
    s += __shfl_xor(s, 16, 64);
    s += __shfl_xor(s, 32, 64);
    if (q == 0 && eg < (long long)B) out[eg] = s + br[0];
}

extern "C" void kernel_launch(void* const* d_in, const int* in_sizes, int n_in,
                              void* d_out, int out_size, void* d_ws, size_t ws_size,
                              hipStream_t stream) {
    const float* x  = (const float*)d_in[0];
    const float* Wf = (const float*)d_in[1];
    const float* bf = (const float*)d_in[2];
    const float* Wm = (const float*)d_in[3];
    const float* bm = (const float*)d_in[4];
    const float* Wu = (const float*)d_in[5];
    const float* bu = (const float*)d_in[6];
    const float* Wr = (const float*)d_in[7];
    const float* br = (const float*)d_in[8];
    float* out = (float*)d_out;
    const int B = in_sizes[0] / 30;

    uint32_t* ws = (uint32_t*)d_ws;           // needs 10 KB; ws_size is ~MBs
    prep_kernel<<<1, 640, 0, stream>>>(Wf, bf, Wm, bm, Wu, bu, ws);
    const int grid = (B + 63) / 64;
    mp_mfma<<<grid, 256, 0, stream>>>(x, Wr, br, ws, out, B);
}